// Round 12
// baseline (425.701 us; speedup 1.0000x reference)
//
#include <hip/hip_runtime.h>
#include <math.h>

#define NJ 17
#define XS 132      // fp32 row stride for sX (floats)
#define LBS 264     // ushort row stride for sLb/sRb
#define XBS 136     // ushort row stride for sXh/sVb (16B-aligned rows)
#define SS 17       // score row stride (floats)
#define TOKE (NJ*128)

typedef unsigned short ushort_t;
typedef unsigned int uint_t;
typedef __attribute__((ext_vector_type(8))) short short8;
typedef __attribute__((ext_vector_type(4))) float f32x4;

// adjacency bitmasks (both dirs + diag)
__device__ __constant__ unsigned int ADJM[NJ] = {
    0x93u, 0x7u, 0xEu, 0xCu, 0x31u, 0x70u, 0x60u,
    0x181u, 0x4B80u, 0x700u, 0x600u, 0x1900u, 0x3800u, 0x3000u,
    0xC100u, 0x1C000u, 0x18000u
};
// dense list of the 49 adjacent (i,j) pairs, packed (i<<8)|j
__device__ __constant__ unsigned short PAIR[49] = {
    0x0000,0x0001,0x0004,0x0007, 0x0100,0x0101,0x0102, 0x0201,0x0202,0x0203,
    0x0302,0x0303, 0x0400,0x0404,0x0405, 0x0504,0x0505,0x0506, 0x0605,0x0606,
    0x0700,0x0707,0x0708, 0x0807,0x0808,0x0809,0x080B,0x080E, 0x0908,0x0909,0x090A,
    0x0A09,0x0A0A, 0x0B08,0x0B0B,0x0B0C, 0x0C0B,0x0C0C,0x0C0D, 0x0D0C,0x0D0D,
    0x0E08,0x0E0E,0x0E0F, 0x0F0E,0x0F0F,0x0F10, 0x100F,0x1010
};

__device__ __forceinline__ uint_t f2bf(float v){
    uint_t u = __float_as_uint(v);
    return (u + 0x7FFFu + ((u >> 16) & 1u)) >> 16;
}
__device__ __forceinline__ float bf2f(uint_t h){ return __uint_as_float(h << 16); }
__device__ __forceinline__ float bflo(uint_t u){ return __uint_as_float(u << 16); }
__device__ __forceinline__ float bfhi(uint_t u){ return __uint_as_float(u & 0xFFFF0000u); }
__device__ __forceinline__ float lrelu02(float u){ return fmaxf(u, 0.f) + 0.2f*fminf(u, 0.f); }
__device__ __forceinline__ float gelu_exact(float x){ return 0.5f*x*(1.f + erff(x*0.70710678118654752f)); }
// packed RNE f32->bf16x2 (gfx950 v_cvt_pk_bf16_f32; RNE == f2bf semantics)
__device__ __forceinline__ uint_t cvtpk(float lo, float hi){
    uint_t r;
    asm("v_cvt_pk_bf16_f32 %0, %1, %2" : "=v"(r) : "v"(lo), "v"(hi));
    return r;
}

// prep: WT[f][k] bf16-hi (f: 0..255 w1-col, 256..511 w2-col, 512..639 vw-col) + bcat
// (wlo kept in workspace layout for compatibility; unused since r9)
__global__ void prep_kernel(const float* __restrict__ w1, const float* __restrict__ b1,
                            const float* __restrict__ w2, const float* __restrict__ b2,
                            const float* __restrict__ vw, const float* __restrict__ vb,
                            ushort_t* __restrict__ whi, ushort_t* __restrict__ wlo,
                            float* __restrict__ bcat){
    int gid = blockIdx.x*256 + threadIdx.x;
    if (gid < 640*128){
        int f = gid >> 7, k = gid & 127;
        float v;
        if (f < 256)      v = w1[k*256 + f];
        else if (f < 512) v = w2[k*256 + (f-256)];
        else              v = vw[k*128 + (f-512)];
        uint_t h = f2bf(v);
        whi[gid] = (ushort_t)h;
        wlo[gid] = (ushort_t)f2bf(v - bf2f(h));
    }
    if (gid < 640){
        float b;
        if (gid < 256)      b = b1[gid];
        else if (gid < 512) b = b2[gid-256];
        else                b = vb[gid-512];
        bcat[gid] = b;
    }
}

// r12: r11 micro-bundle (numerics-preserving):
//   (1) v_cvt_pk_bf16_f32 for all bf16 packing (same RNE as f2bf; 3 ops -> 1,
//       lower temp pressure -> should shrink r11's small spill).
//   (2) phase (c): 4 accumulator chains (halves the 64-deep dependent-fma chain;
//       fp32 reassociation only, r1 precedent).
//   (3) __expf in sigmoid gate + softmax (~1e-6 rel).
// Everything else byte-identical to r11 (369.7 us, absmax 0.0234, VGPR 84,
// occupancy 29.8% = 3 blocks/CU).
// LDS 11,972 f = 47,888 B -> 48,128 alloc (3x = 144,384, r0-proven envelope).
// Alias lifetimes:
//   sLb over sXa      : old x dead after (a); rewritten by (e).
//   sRb over sXh+pad  : xn-hi dead after (b)'s fragment loads (barrier in (b)).
//   sS  over sRb      : l/r dead after (c)'s reads (barrier in (c)).
__attribute__((amdgpu_flat_work_group_size(256, 256), amdgpu_waves_per_eu(3)))
__global__ void appnp_kernel(const float* __restrict__ x,
                  const float* __restrict__ og, const float* __restrict__ ob,
                  const float* __restrict__ lg, const float* __restrict__ lb,
                  const float* __restrict__ aw, const float* __restrict__ ab,
                  const float* __restrict__ psw, const float* __restrict__ psb,
                  const ushort_t* __restrict__ whi, const ushort_t* __restrict__ wlo,
                  const float* __restrict__ bcat,
                  float* __restrict__ out)
{
    __shared__ __align__(16) float smem[11972];
    float*    sXa  = smem;                            // [0,4488)  2x2244 f state x [sLb alias]
    ushort_t* sLb  = (ushort_t*)smem;                 //   2x4488 ush l bf16 (ALIAS sXa)
    ushort_t* sXh  = (ushort_t*)(smem + 4488);        // region B: 2x2312 ush xn bf16-hi
    ushort_t* sRb  = (ushort_t*)(smem + 4488);        //   2x4488 ush r bf16 (ALIAS sXh+pad)
    float*    sS   = smem + 4488;                     //   2x578 f scores (ALIAS sRb, after (c))
    ushort_t* sVb  = (ushort_t*)(smem + 9112);        // [9112,11424) 2x2312 ush V bf16
    float*    sK   = smem + 11424;                    // 2 x 18
    float*    sLG  = smem + 11460;                    // 128
    float*    sLBt = smem + 11588;                    // 128
    float*    sPW  = smem + 11716;                    // 128
    float*    sAW  = smem + 11844;                    // 128  -> total 11,972 f = 47,888 B

    const int t = threadIdx.x;
    const int wave = t >> 6, lane = t & 63, l16 = lane & 15, quad = lane >> 4;
    const long long base = (long long)blockIdx.x * (2*TOKE);

    // uniform scalars (L2-resident s_load)
    const float abv  = ab[0];
    const float psbv = psb[0];

    // ---- stage small params ----
    if (t < 128){ sLG[t] = lg[t]; sLBt[t] = lb[t]; sPW[t] = psw[t]; sAW[t] = aw[t]; }

    // ---- load x for 2 tokens (1088 float4 groups, contiguous) ----
    for (int idx = t; idx < 1088; idx += 256){
        int r2 = idx >> 5, c = (idx & 31) << 2;
        int tau = (r2 >= NJ), r = r2 - NJ*tau;
        *(float4*)(sXa + tau*2244 + r*XS + c) = *(const float4*)(x + base + idx*4);
    }
    __syncthreads();

    // ---- outer LN -> sX in place; x0 copy -> out (global, read back in (e)) ----
    #pragma unroll
    for (int p = 0; p < 5; p++){
        int idx = t + (p << 8);
        if (p < 4 || t < 64){
            int r2 = idx >> 5, c = (idx & 31) << 2;
            int tau = (r2 >= NJ), r = r2 - NJ*tau;
            float* px = sXa + tau*2244 + r*XS + c;
            float4 v = *(float4*)px;
            float s = v.x + v.y + v.z + v.w;
            float q = v.x*v.x + v.y*v.y + v.z*v.z + v.w*v.w;
            #pragma unroll
            for (int m = 1; m <= 16; m <<= 1){ s += __shfl_xor(s, m); q += __shfl_xor(q, m); }
            float mu = s * (1.f/128.f);
            float rs = rsqrtf(q * (1.f/128.f) - mu*mu + 1e-5f);
            float4 g = *(const float4*)(og + c);
            float4 b = *(const float4*)(ob + c);
            float4 nv;
            nv.x = (v.x-mu)*rs*g.x + b.x;  nv.y = (v.y-mu)*rs*g.y + b.y;
            nv.z = (v.z-mu)*rs*g.z + b.z;  nv.w = (v.w-mu)*rs*g.w + b.w;
            *(float4*)px = nv;
            *(float4*)(out + base + idx*4) = nv;   // x0 parked in out until final store
        }
    }
    __syncthreads();

    for (int it = 0; it < 4; it++){
        // ---- (a) inner LN -> sXh bf16 (RNE via cvt_pk) + fused skip gate ----
        {
            #pragma unroll
            for (int p = 0; p < 5; p++){
                int idx = t + (p << 8);
                if (p < 4 || t < 64){
                    int r2 = idx >> 5, c = (idx & 31) << 2;
                    int tau = (r2 >= NJ), r = r2 - NJ*tau;
                    float4 v = *(const float4*)(sXa + tau*2244 + r*XS + c);
                    float s = v.x + v.y + v.z + v.w;
                    float q = v.x*v.x + v.y*v.y + v.z*v.z + v.w*v.w;
                    #pragma unroll
                    for (int m = 1; m <= 16; m <<= 1){ s += __shfl_xor(s, m); q += __shfl_xor(q, m); }
                    float mu = s * (1.f/128.f);
                    float rs = rsqrtf(q * (1.f/128.f) - mu*mu + 1e-5f);
                    float4 g = *(const float4*)(sLG + c);
                    float4 b = *(const float4*)(sLBt + c);
                    float n0 = (v.x-mu)*rs*g.x + b.x, n1 = (v.y-mu)*rs*g.y + b.y;
                    float n2 = (v.z-mu)*rs*g.z + b.z, n3 = (v.w-mu)*rs*g.w + b.w;
                    uint2 ph;
                    ph.x = cvtpk(n0, n1);
                    ph.y = cvtpk(n2, n3);
                    *(uint2*)(sXh + tau*2312 + r*XBS + c) = ph;
                    float4 a = *(const float4*)(sAW + c);
                    float sp = n0*a.x + n1*a.y + n2*a.z + n3*a.w;
                    #pragma unroll
                    for (int m = 1; m <= 16; m <<= 1) sp += __shfl_xor(sp, m);
                    if ((t & 31) == 0) sK[tau*18 + r] = 1.f / (1.f + __expf(-(sp + abv)));
                }
            }
        }
        __syncthreads();

        // ---- (b) MFMA GEMM (pure bf16): B0/B1 = tokens' rows 0..15; B2 = rows 16 ----
        {
            short8 B0h[4], B1h[4], B2h[4];
            const int fo = l16*XBS + quad*8;
            #pragma unroll
            for (int ks = 0; ks < 4; ks++){
                B0h[ks] = *(const short8*)(sXh + fo + ks*32);
                B1h[ks] = *(const short8*)(sXh + 2312 + fo + ks*32);
            }
            const int btau = l16 & 1;   // col 0 -> t0 row16, col 1 -> t1 row16 (others dup, unused)
            const int f16o = btau*2312 + 16*XBS + quad*8;
            #pragma unroll
            for (int ks = 0; ks < 4; ks++)
                B2h[ks] = *(const short8*)(sXh + f16o + ks*32);
            // sXh now dead; sRb aliases it -> all waves must pass here before writes
            __syncthreads();
            const int fbase = wave * 160;
            #pragma unroll 2
            for (int ft = 0; ft < 10; ft++){
                int f0 = fbase + ft*16;
                const ushort_t* ah = whi + (f0 + l16)*128 + quad*8;
                short8 Ah[4];
                #pragma unroll
                for (int ks = 0; ks < 4; ks++)
                    Ah[ks] = *(const short8*)(ah + ks*32);
                float4 bb = *(const float4*)(bcat + f0 + quad*4);
                f32x4 a0, a1, a2;
                a0[0] = bb.x; a0[1] = bb.y; a0[2] = bb.z; a0[3] = bb.w;
                a1 = a0; a2 = a0;
                #pragma unroll
                for (int ks = 0; ks < 4; ks++){
                    a0 = __builtin_amdgcn_mfma_f32_16x16x32_bf16(Ah[ks], B0h[ks], a0, 0, 0, 0);
                    a1 = __builtin_amdgcn_mfma_f32_16x16x32_bf16(Ah[ks], B1h[ks], a1, 0, 0, 0);
                    a2 = __builtin_amdgcn_mfma_f32_16x16x32_bf16(Ah[ks], B2h[ks], a2, 0, 0, 0);
                }
                int fb = f0 + quad*4;
                if (f0 < 512){
                    ushort_t* bse; int col;
                    if (f0 < 256){ bse = sLb; col = fb; } else { bse = sRb; col = fb - 256; }
                    uint2 p0;
                    p0.x = cvtpk(a0[0], a0[1]);
                    p0.y = cvtpk(a0[2], a0[3]);
                    *(uint2*)(bse + l16*LBS + col) = p0;
                    uint2 p1;
                    p1.x = cvtpk(a1[0], a1[1]);
                    p1.y = cvtpk(a1[2], a1[3]);
                    *(uint2*)(bse + 4488 + l16*LBS + col) = p1;
                    if (l16 < 2){
                        uint2 p2;
                        p2.x = cvtpk(a2[0], a2[1]);
                        p2.y = cvtpk(a2[2], a2[3]);
                        *(uint2*)(bse + btau*4488 + 16*LBS + col) = p2;
                    }
                } else {
                    int col = fb - 512;
                    uint2 q0;
                    q0.x = cvtpk(a0[0], a0[1]);
                    q0.y = cvtpk(a0[2], a0[3]);
                    *(uint2*)(sVb + l16*XBS + col) = q0;
                    uint2 q1;
                    q1.x = cvtpk(a1[0], a1[1]);
                    q1.y = cvtpk(a1[2], a1[3]);
                    *(uint2*)(sVb + 2312 + l16*XBS + col) = q1;
                    if (l16 < 2){
                        uint2 q2;
                        q2.x = cvtpk(a2[0], a2[1]);
                        q2.y = cvtpk(a2[2], a2[3]);
                        *(uint2*)(sVb + btau*2312 + 16*XBS + col) = q2;
                    }
                }
            }
        }
        __syncthreads();

        // ---- (c) attention scores: 2 tok x 2 head x 49 pairs = 196 tasks ----
        // 4 accumulator chains (16-deep each). Stage 1: read sLb/sRb into regs.
        // Stage 2 (after barrier): write sS over sRb.
        {
            float accv = 0.f; int sidx = 0;
            if (t < 196){
                int tau = (t >= 98); int th = t - 98*tau;
                int h = (th >= 49);  int p = th - 49*h;
                unsigned short pr = PAIR[p];
                int i = pr >> 8, j = pr & 255;
                const uint4* lp = (const uint4*)(sLb + tau*4488 + i*LBS + h*128);
                const uint4* rp = (const uint4*)(sRb + tau*4488 + j*LBS + h*128);
                float accA = 0.f, accB = 0.f, accC = 0.f, accD = 0.f;
                #pragma unroll
                for (int d = 0; d < 16; d++){
                    uint4 lu = lp[d], ru = rp[d];
                    float4 p0 = *(const float4*)(sPW + d*8);
                    float4 p1 = *(const float4*)(sPW + d*8 + 4);
                    accA += lrelu02(bflo(lu.x) + bflo(ru.x)) * p0.x;
                    accB += lrelu02(bfhi(lu.x) + bfhi(ru.x)) * p0.y;
                    accC += lrelu02(bflo(lu.y) + bflo(ru.y)) * p0.z;
                    accD += lrelu02(bfhi(lu.y) + bfhi(ru.y)) * p0.w;
                    accA += lrelu02(bflo(lu.z) + bflo(ru.z)) * p1.x;
                    accB += lrelu02(bfhi(lu.z) + bfhi(ru.z)) * p1.y;
                    accC += lrelu02(bflo(lu.w) + bflo(ru.w)) * p1.z;
                    accD += lrelu02(bfhi(lu.w) + bfhi(ru.w)) * p1.w;
                }
                accv = ((accA + accB) + (accC + accD)) + psbv;
                sidx = tau*578 + (h*NJ + i)*SS + j;
            }
            __syncthreads();   // drain all sLb/sRb reads before sS overlays sRb
            if (t < 196) sS[sidx] = accv;
        }
        __syncthreads();

        // ---- (d) masked softmax: 2 tok x 34 rows, 2 lanes/row parity split ----
        if (t < 136){
            int rid = t >> 1, sub = t & 1;
            int tau = (rid >= 34); int r34 = rid - 34*tau;
            int h = (r34 >= NJ);   int i = r34 - NJ*h;
            float* sp = sS + tau*578 + (h*NJ + i)*SS;
            unsigned int m = ADJM[i];
            float mx = -1e30f;
            #pragma unroll
            for (int jj = 0; jj < 9; jj++){
                int j = 2*jj + sub;
                if (j < NJ && ((m >> j) & 1u)) mx = fmaxf(mx, sp[j]);
            }
            mx = fmaxf(mx, __shfl_xor(mx, 1));
            float pv[9]; float sum = 0.f;
            #pragma unroll
            for (int jj = 0; jj < 9; jj++){
                int j = 2*jj + sub;
                if (j < NJ && ((m >> j) & 1u)){ pv[jj] = __expf(sp[j] - mx); sum += pv[jj]; }
                else pv[jj] = 0.f;
            }
            sum += __shfl_xor(sum, 1);
            float inv = 1.f / sum;
            #pragma unroll
            for (int jj = 0; jj < 9; jj++){
                int j = 2*jj + sub;
                if (j < NJ) sp[j] = pv[jj]*inv;
            }
        }
        __syncthreads();

        // ---- (e) PV (bf16 V) + gelu + blend (x0 from out) -> new x in sX ----
        #pragma unroll
        for (int p = 0; p < 5; p++){
            int idx = t + (p << 8);
            if (p < 4 || t < 64){
                int r2 = idx >> 5, cg = idx & 31;
                int tau = (r2 >= NJ), r = r2 - NJ*tau;
                int c = cg << 2, h = cg >> 4;
                float4 x0v = *(const float4*)(out + base + idx*4);   // issue early; L2-hot
                const float* sp = sS + tau*578 + (h*NJ + r)*SS;
                const ushort_t* vp = sVb + tau*2312 + c;
                float a0 = 0.f, a1 = 0.f, a2 = 0.f, a3 = 0.f;
                #pragma unroll
                for (int j = 0; j < NJ; j++){
                    float pj = sp[j];
                    uint2 vv = *(const uint2*)(vp + j*XBS);
                    a0 += pj*bflo(vv.x); a1 += pj*bfhi(vv.x);
                    a2 += pj*bflo(vv.y); a3 += pj*bfhi(vv.y);
                }
                a0 = gelu_exact(a0); a1 = gelu_exact(a1); a2 = gelu_exact(a2); a3 = gelu_exact(a3);
                float sk = sK[tau*18 + r];
                float4 nx;
                nx.x = (1.f-sk)*a0 + sk*x0v.x;  nx.y = (1.f-sk)*a1 + sk*x0v.y;
                nx.z = (1.f-sk)*a2 + sk*x0v.z;  nx.w = (1.f-sk)*a3 + sk*x0v.w;
                *(float4*)(sXa + tau*2244 + r*XS + c) = nx;
            }
        }
        __syncthreads();
    }

    // ---- store (overwrites the x0 copy) ----
    for (int idx = t; idx < 1088; idx += 256){
        int r2 = idx >> 5, c = (idx & 31) << 2;
        int tau = (r2 >= NJ), r = r2 - NJ*tau;
        *(float4*)(out + base + idx*4) = *(const float4*)(sXa + tau*2244 + r*XS + c);
    }
}

extern "C" void kernel_launch(void* const* d_in, const int* in_sizes, int n_in,
                              void* d_out, int out_size, void* d_ws, size_t ws_size,
                              hipStream_t stream) {
    const float* x   = (const float*)d_in[0];
    const float* og  = (const float*)d_in[1];
    const float* ob  = (const float*)d_in[2];
    const float* lg  = (const float*)d_in[3];
    const float* lb  = (const float*)d_in[4];
    const float* aw  = (const float*)d_in[5];
    const float* ab  = (const float*)d_in[6];
    const float* w1  = (const float*)d_in[7];
    const float* b1  = (const float*)d_in[8];
    const float* w2  = (const float*)d_in[9];
    const float* b2  = (const float*)d_in[10];
    const float* psw = (const float*)d_in[11];
    const float* psb = (const float*)d_in[12];
    const float* vw  = (const float*)d_in[13];
    const float* vb  = (const float*)d_in[14];
    float* out = (float*)d_out;

    // workspace: whi (640*128 bf16) + wlo (640*128 bf16) + bcat (640 f32) = 330,240 B
    ushort_t* whi = (ushort_t*)d_ws;
    ushort_t* wlo = whi + 640*128;
    float* bcat = (float*)(wlo + 640*128);

    prep_kernel<<<dim3(320), dim3(256), 0, stream>>>(w1, b1, w2, b2, vw, vb, whi, wlo, bcat);

    int BT = in_sizes[0] / TOKE;   // 3888 tokens
    appnp_kernel<<<dim3(BT/2), dim3(256), 0, stream>>>(
        x, og, ob, lg, lb, aw, ab, psw, psb, whi, wlo, bcat, out);
}